// Round 1
// baseline (276.434 us; speedup 1.0000x reference)
//
#include <hip/hip_runtime.h>

namespace {

constexpr int N = 30;      // nodes
constexpr int H = 32;      // hidden
constexpr int D = 3;       // dims
constexpr int PAD = 4;     // LDS row pad (keeps 16B align, spreads banks)
constexpr int NPAIR = N * N;           // 900 incl. diagonal (skipped)
constexpr float INV_CNT = 1.0f / 29.0f;

__global__ __launch_bounds__(256, 4) void gnn2_fused(
    const float* __restrict__ x,                          // (B,N,D)
    const float* __restrict__ W1, const float* __restrict__ b1,   // (6,H),(H)
    const float* __restrict__ W2, const float* __restrict__ b2,   // (H,H),(H)
    const float* __restrict__ W3, const float* __restrict__ b3,   // (H,H),(H)
    const float* __restrict__ W4, const float* __restrict__ b4,   // (2H,H),(H)
    const float* __restrict__ W5, const float* __restrict__ b5,   // (H,H),(H)
    const float* __restrict__ W6, const float* __restrict__ b6,   // (H,D),(D)
    float* __restrict__ out)                              // (B,N,D)
{
    __shared__ float uS[N][H + PAD];    // u[i] = x_i @ (W1a-W1b) + b1   (later reused for layer 2)
    __shared__ float vS[N][H + PAD];    // v[j] = x_j @ W1b
    __shared__ float aggS[N][H + PAD];  // layer-1 aggregation
    __shared__ float outS[N][D];        // layer-2 aggregation

    const int b = blockIdx.x;
    const int t = threadIdx.x;
    const float* xb = x + b * (N * D);

    // ---------- Phase 1: per-node u,v for layer 1 ----------
    if (t < N * 8) {
        const int i = t >> 3, g = t & 7;
        const float x0 = xb[i * D + 0], x1 = xb[i * D + 1], x2 = xb[i * D + 2];
#pragma unroll
        for (int ff = 0; ff < 4; ++ff) {
            const int f = g + 8 * ff;
            const float wa0 = W1[0 * H + f], wa1 = W1[1 * H + f], wa2 = W1[2 * H + f];
            const float wb0 = W1[3 * H + f], wb1 = W1[4 * H + f], wb2 = W1[5 * H + f];
            vS[i][f] = x0 * wb0 + x1 * wb1 + x2 * wb2;
            uS[i][f] = x0 * (wa0 - wb0) + x1 * (wa1 - wb1) + x2 * (wa2 - wb2) + b1[f];
        }
    }
#pragma unroll 1
    for (int idx = t; idx < N * (H + PAD); idx += 256) (&aggS[0][0])[idx] = 0.0f;
    __syncthreads();

    // ---------- Phase 2: layer-1 edge MLP over all (i,j), i = p%N (j-major) ----------
#pragma unroll 1
    for (int p = t; p < NPAIR; p += 256) {
        const int i = p % N;          // receiving node: consecutive lanes -> distinct i
        const int j = p / N;          // source node: uniform across consecutive lanes
        if (i == j) continue;
        float t1[H];
#pragma unroll
        for (int k = 0; k < H; ++k) t1[k] = fmaxf(uS[i][k] + vS[j][k], 0.0f);
        float t2[H];
#pragma unroll
        for (int f = 0; f < H; ++f) {
            float acc = b2[f];
#pragma unroll
            for (int k = 0; k < H; ++k) acc = fmaf(t1[k], W2[k * H + f], acc);
            t2[f] = fmaxf(acc, 0.0f);
        }
#pragma unroll
        for (int f = 0; f < H; ++f) {
            float acc = b3[f];
#pragma unroll
            for (int k = 0; k < H; ++k) acc = fmaf(t2[k], W3[k * H + f], acc);
            atomicAdd(&aggS[i][f], acc);
        }
    }
    __syncthreads();

    // ---------- Phase 3: h = agg/29 ; per-node u2,v2 for layer 2 (reuse uS/vS) ----------
    if (t < N * D) (&outS[0][0])[t] = 0.0f;
    if (t < N * 8) {
        const int i = t >> 3, g = t & 7;
        float h[H];
#pragma unroll
        for (int k = 0; k < H; ++k) h[k] = aggS[i][k] * INV_CNT;
#pragma unroll
        for (int ff = 0; ff < 4; ++ff) {
            const int f = g + 8 * ff;
            float au = b4[f], av = 0.0f;
#pragma unroll
            for (int k = 0; k < H; ++k) {
                const float wa = W4[k * H + f];
                const float wb = W4[(H + k) * H + f];
                au = fmaf(h[k], wa - wb, au);
                av = fmaf(h[k], wb, av);
            }
            uS[i][f] = au;
            vS[i][f] = av;
        }
    }
    __syncthreads();

    // ---------- Phase 4: layer-2 edge MLP ----------
#pragma unroll 1
    for (int p = t; p < NPAIR; p += 256) {
        const int i = p % N;
        const int j = p / N;
        if (i == j) continue;
        float t1[H];
#pragma unroll
        for (int k = 0; k < H; ++k) t1[k] = fmaxf(uS[i][k] + vS[j][k], 0.0f);
        float t2[H];
#pragma unroll
        for (int f = 0; f < H; ++f) {
            float acc = b5[f];
#pragma unroll
            for (int k = 0; k < H; ++k) acc = fmaf(t1[k], W5[k * H + f], acc);
            t2[f] = fmaxf(acc, 0.0f);
        }
#pragma unroll
        for (int d = 0; d < D; ++d) {
            float acc = b6[d];
#pragma unroll
            for (int k = 0; k < H; ++k) acc = fmaf(t2[k], W6[k * D + d], acc);
            atomicAdd(&outS[i][d], acc);
        }
    }
    __syncthreads();

    // ---------- Write out ----------
    if (t < N * D) {
        out[b * (N * D) + t] = (&outS[0][0])[t] * INV_CNT;
    }
}

} // namespace

extern "C" void kernel_launch(void* const* d_in, const int* in_sizes, int n_in,
                              void* d_out, int out_size, void* d_ws, size_t ws_size,
                              hipStream_t stream) {
    const float* x  = (const float*)d_in[0];
    const float* W1 = (const float*)d_in[1];
    const float* b1 = (const float*)d_in[2];
    const float* W2 = (const float*)d_in[3];
    const float* b2 = (const float*)d_in[4];
    const float* W3 = (const float*)d_in[5];
    const float* b3 = (const float*)d_in[6];
    const float* W4 = (const float*)d_in[7];
    const float* b4 = (const float*)d_in[8];
    const float* W5 = (const float*)d_in[9];
    const float* b5 = (const float*)d_in[10];
    const float* W6 = (const float*)d_in[11];
    const float* b6 = (const float*)d_in[12];
    // edge_index (d_in[13]) is deterministic dense all-pairs; structure is hardcoded.

    const int batch = in_sizes[0] / (N * D);
    float* out = (float*)d_out;

    gnn2_fused<<<dim3(batch), dim3(256), 0, stream>>>(
        x, W1, b1, W2, b2, W3, b3, W4, b4, W5, b5, W6, b6, out);
}

// Round 4
// 260.076 us; speedup vs baseline: 1.0629x; 1.0629x over previous
//
#include <hip/hip_runtime.h>
#include <hip/hip_bf16.h>

namespace {

typedef __attribute__((ext_vector_type(8))) short short8;
typedef __attribute__((ext_vector_type(4))) float float4v;

constexpr int N = 30;              // nodes
constexpr int H = 32;              // hidden
constexpr int D = 3;               // dims
constexpr int NP = N * N;          // 900 pair-rows (p = i*30+j, diagonal masked at scatter)
constexpr int NTILES = (NP + 15) / 16;  // 57 row-tiles of 16
constexpr int PW = H + 4;          // padded LDS row width (words) -> 2-way conflicts max
constexpr float INV_CNT = 1.0f / 29.0f;

__device__ __forceinline__ short bfb(float x) {
    __hip_bfloat16 h = __float2bfloat16(x);   // RNE hardware convert
    return __builtin_bit_cast(short, h);
}

__global__ __launch_bounds__(256, 4) void gnn2_mfma(
    const float* __restrict__ x,
    const float* __restrict__ W1, const float* __restrict__ b1,
    const float* __restrict__ W2, const float* __restrict__ b2,
    const float* __restrict__ W3, const float* __restrict__ b3,
    const float* __restrict__ W4, const float* __restrict__ b4,
    const float* __restrict__ W5, const float* __restrict__ b5,
    const float* __restrict__ W6, const float* __restrict__ b6,
    float* __restrict__ out)
{
    __shared__ float uS[N * PW];        // u[i][f] (layer1), then u2 (layer2)
    __shared__ float vS[N * PW];        // v[j][f]
    __shared__ float aggS[N * PW];      // layer-1 aggregation
    __shared__ float outS[N * 4];       // layer-2 aggregation (padded to 4)
    __shared__ float t2buf[4][16 * PW]; // wave-private T2 tile buffers

    const int b = blockIdx.x;
    const int t = threadIdx.x;
    const int lane = t & 63;
    const int w = t >> 6;            // wave id 0..3
    const int c  = lane & 15;        // tile col  (B col / C col)
    const int g  = lane >> 4;        // k-group (A/B) and row-group (C)
    const int k0 = g * 8;            // contiguous-8 k base for A/B fragments

    // ---------------- persistent B-fragments (bf16) + biases ----------------
    // B layout (16x16x32): lane holds col=c, k = k0..k0+7 contiguous.
    short8 B2h0, B2h1, B3h0, B3h1, B5h0, B5h1, B6f, B4Uh0, B4Uh1, B4Vh0, B4Vh1;
#pragma unroll
    for (int e = 0; e < 8; ++e) {
        const int k = k0 + e;
        B2h0[e] = bfb(W2[k*H + c]);
        B2h1[e] = bfb(W2[k*H + 16 + c]);
        B3h0[e] = bfb(W3[k*H + c]);
        B3h1[e] = bfb(W3[k*H + 16 + c]);
        B5h0[e] = bfb(W5[k*H + c]);
        B5h1[e] = bfb(W5[k*H + 16 + c]);
        B6f[e]  = bfb(c < D ? W6[k*D + c] : 0.0f);
        const float wb0 = W4[(H + k)*H + c];
        const float wb1 = W4[(H + k)*H + 16 + c];
        B4Uh0[e] = bfb(W4[k*H + c]      - wb0);   // W4a - W4b
        B4Uh1[e] = bfb(W4[k*H + 16 + c] - wb1);
        B4Vh0[e] = bfb(wb0);                      // W4b
        B4Vh1[e] = bfb(wb1);
    }
    const float bb2a = b2[c], bb2b = b2[16+c];
    const float bb3a = b3[c], bb3b = b3[16+c];
    const float bb5a = b5[c], bb5b = b5[16+c];
    const float bb4a = b4[c], bb4b = b4[16+c];
    const float bb6  = (c < D) ? b6[c] : 0.0f;

    // ---------------- Phase A: per-node u,v (fp32, factored W1) ----------------
    const float* xb = x + b * (N * D);
    if (t < N * 8) {
        const int i = t >> 3, gg = t & 7;
        const float x0 = xb[i*D+0], x1 = xb[i*D+1], x2 = xb[i*D+2];
#pragma unroll
        for (int ff = 0; ff < 4; ++ff) {
            const int f = gg + 8 * ff;
            const float wa0 = W1[0*H+f], wa1 = W1[1*H+f], wa2 = W1[2*H+f];
            const float wb0 = W1[3*H+f], wb1 = W1[4*H+f], wb2 = W1[5*H+f];
            vS[i*PW+f] = x0*wb0 + x1*wb1 + x2*wb2;
            uS[i*PW+f] = x0*(wa0-wb0) + x1*(wa1-wb1) + x2*(wa2-wb2) + b1[f];
        }
    }
#pragma unroll 1
    for (int idx = t; idx < N*PW; idx += 256) aggS[idx] = 0.0f;
    if (t < N*4) outS[t] = 0.0f;
    __syncthreads();

    float* const myt2 = t2buf[w];

    // ---------------- Layer 1: edge MLP via MFMA over row-tiles ----------------
#pragma unroll 1
    for (int tile = w; tile < NTILES; tile += 4) {
        const int p0 = tile * 16;
        // A-fragment: row = p0 + c, k = k0..k0+7 ; t1 = relu(u[i]+v[j])
        int ra = p0 + c; ra = (ra < NP - 1) ? ra : (NP - 1);
        const int ia = ra / N, ja = ra - ia * N;
        short8 a;
#pragma unroll
        for (int e = 0; e < 8; ++e) {
            const float tv = uS[ia*PW + k0 + e] + vS[ja*PW + k0 + e];
            a[e] = bfb(fmaxf(tv, 0.0f));
        }
        float4v acc0 = {bb2a, bb2a, bb2a, bb2a};
        float4v acc1 = {bb2b, bb2b, bb2b, bb2b};
        acc0 = __builtin_amdgcn_mfma_f32_16x16x32_bf16(a, B2h0, acc0, 0, 0, 0);
        acc1 = __builtin_amdgcn_mfma_f32_16x16x32_bf16(a, B2h1, acc1, 0, 0, 0);
        // relu + wave-private LDS round-trip (C layout -> A layout)
#pragma unroll
        for (int r = 0; r < 4; ++r) {
            myt2[(g*4+r)*PW + c]      = fmaxf(acc0[r], 0.0f);
            myt2[(g*4+r)*PW + 16 + c] = fmaxf(acc1[r], 0.0f);
        }
        short8 a2;
#pragma unroll
        for (int e = 0; e < 8; ++e) a2[e] = bfb(myt2[c*PW + k0 + e]);
        acc0 = (float4v){bb3a, bb3a, bb3a, bb3a};
        acc1 = (float4v){bb3b, bb3b, bb3b, bb3b};
        acc0 = __builtin_amdgcn_mfma_f32_16x16x32_bf16(a2, B3h0, acc0, 0, 0, 0);
        acc1 = __builtin_amdgcn_mfma_f32_16x16x32_bf16(a2, B3h1, acc1, 0, 0, 0);
        // scatter: C row = p0 + g*4 + r, col = c / c+16 ; skip diagonal + tail
#pragma unroll
        for (int r = 0; r < 4; ++r) {
            const int row = p0 + g*4 + r;
            const int i = row / N, j = row - i * N;
            if (row < NP && i != j) {
                atomicAdd(&aggS[i*PW + c],      acc0[r]);
                atomicAdd(&aggS[i*PW + 16 + c], acc1[r]);
            }
        }
    }
    __syncthreads();

    // ---------------- Phase C: h = agg/29 ; u2,v2 = h@W4 (factored) via MFMA ----------------
    {
        const int mat = w >> 1;      // 0: U-gemm (W4a-W4b,+b4), 1: V-gemm (W4b)
        const int tl  = w & 1;       // row-tile 0: rows 0-15, 1: rows 16-29
        int ra = tl * 16 + c; ra = (ra < N - 1) ? ra : (N - 1);
        short8 a;
#pragma unroll
        for (int e = 0; e < 8; ++e) a[e] = bfb(aggS[ra*PW + k0 + e] * INV_CNT);
        float4v acc0, acc1;
        if (mat == 0) {
            acc0 = (float4v){bb4a, bb4a, bb4a, bb4a};
            acc1 = (float4v){bb4b, bb4b, bb4b, bb4b};
            acc0 = __builtin_amdgcn_mfma_f32_16x16x32_bf16(a, B4Uh0, acc0, 0, 0, 0);
            acc1 = __builtin_amdgcn_mfma_f32_16x16x32_bf16(a, B4Uh1, acc1, 0, 0, 0);
        } else {
            acc0 = (float4v){0.f, 0.f, 0.f, 0.f};
            acc1 = (float4v){0.f, 0.f, 0.f, 0.f};
            acc0 = __builtin_amdgcn_mfma_f32_16x16x32_bf16(a, B4Vh0, acc0, 0, 0, 0);
            acc1 = __builtin_amdgcn_mfma_f32_16x16x32_bf16(a, B4Vh1, acc1, 0, 0, 0);
        }
        float* const dst = (mat == 0) ? uS : vS;
#pragma unroll
        for (int r = 0; r < 4; ++r) {
            const int row = tl * 16 + g*4 + r;
            if (row < N) {
                dst[row*PW + c]      = acc0[r];
                dst[row*PW + 16 + c] = acc1[r];
            }
        }
    }
    __syncthreads();

    // ---------------- Layer 2: edge MLP via MFMA (W5 then W6->3 cols) ----------------
#pragma unroll 1
    for (int tile = w; tile < NTILES; tile += 4) {
        const int p0 = tile * 16;
        int ra = p0 + c; ra = (ra < NP - 1) ? ra : (NP - 1);
        const int ia = ra / N, ja = ra - ia * N;
        short8 a;
#pragma unroll
        for (int e = 0; e < 8; ++e) {
            const float tv = uS[ia*PW + k0 + e] + vS[ja*PW + k0 + e];
            a[e] = bfb(fmaxf(tv, 0.0f));
        }
        float4v acc0 = {bb5a, bb5a, bb5a, bb5a};
        float4v acc1 = {bb5b, bb5b, bb5b, bb5b};
        acc0 = __builtin_amdgcn_mfma_f32_16x16x32_bf16(a, B5h0, acc0, 0, 0, 0);
        acc1 = __builtin_amdgcn_mfma_f32_16x16x32_bf16(a, B5h1, acc1, 0, 0, 0);
#pragma unroll
        for (int r = 0; r < 4; ++r) {
            myt2[(g*4+r)*PW + c]      = fmaxf(acc0[r], 0.0f);
            myt2[(g*4+r)*PW + 16 + c] = fmaxf(acc1[r], 0.0f);
        }
        short8 a2;
#pragma unroll
        for (int e = 0; e < 8; ++e) a2[e] = bfb(myt2[c*PW + k0 + e]);
        float4v acc2 = {bb6, bb6, bb6, bb6};
        acc2 = __builtin_amdgcn_mfma_f32_16x16x32_bf16(a2, B6f, acc2, 0, 0, 0);
        if (c < D) {
#pragma unroll
            for (int r = 0; r < 4; ++r) {
                const int row = p0 + g*4 + r;
                const int i = row / N, j = row - i * N;
                if (row < NP && i != j) atomicAdd(&outS[i*4 + c], acc2[r]);
            }
        }
    }
    __syncthreads();

    // ---------------- Write out ----------------
    if (t < N * D) {
        const int i = t / D, dd = t - i * D;
        out[b * (N*D) + t] = outS[i*4 + dd] * INV_CNT;
    }
}

} // namespace

extern "C" void kernel_launch(void* const* d_in, const int* in_sizes, int n_in,
                              void* d_out, int out_size, void* d_ws, size_t ws_size,
                              hipStream_t stream) {
    const float* x  = (const float*)d_in[0];
    const float* W1 = (const float*)d_in[1];
    const float* b1 = (const float*)d_in[2];
    const float* W2 = (const float*)d_in[3];
    const float* b2 = (const float*)d_in[4];
    const float* W3 = (const float*)d_in[5];
    const float* b3 = (const float*)d_in[6];
    const float* W4 = (const float*)d_in[7];
    const float* b4 = (const float*)d_in[8];
    const float* W5 = (const float*)d_in[9];
    const float* b5 = (const float*)d_in[10];
    const float* W6 = (const float*)d_in[11];
    const float* b6 = (const float*)d_in[12];
    // d_in[13] = edge_index: dense all-pairs, structure hardcoded.

    const int batch = in_sizes[0] / (N * D);
    float* out = (float*)d_out;

    gnn2_mfma<<<dim3(batch), dim3(256), 0, stream>>>(
        x, W1, b1, W2, b2, W3, b3, W4, b4, W5, b5, W6, b6, out);
}

// Round 6
// 111.350 us; speedup vs baseline: 2.4826x; 2.3357x over previous
//
#include <hip/hip_runtime.h>
#include <hip/hip_bf16.h>

namespace {

typedef __attribute__((ext_vector_type(8))) short short8;
typedef __attribute__((ext_vector_type(16))) float float16v;

constexpr int N = 30;              // nodes
constexpr int H = 32;              // hidden
constexpr int D = 3;               // dims
constexpr int PW = H + 4;          // LDS row stride (words)
constexpr float INV_CNT = 1.0f / 29.0f;

__device__ __forceinline__ short bfb(float x) {
    __hip_bfloat16 h = __float2bfloat16(x);   // RNE hardware convert
    return __builtin_bit_cast(short, h);
}

__device__ __forceinline__ float16v mfma32(short8 a, short8 b, float16v c) {
    return __builtin_amdgcn_mfma_f32_32x32x16_bf16(a, b, c, 0, 0, 0);
}

// One batch element per block. Per node i: its 30 pair-rows form ONE 32x32 MFMA
// tile (rows j=0..29 = source node, 2 pad rows). Aggregation over j == column-sum
// of that tile (diagonal/pad excluded by zeroing A rows; biases applied post-agg).
__global__ __launch_bounds__(256, 4) void gnn2_v2(
    const float* __restrict__ x,
    const float* __restrict__ W1, const float* __restrict__ b1,
    const float* __restrict__ W2, const float* __restrict__ b2,
    const float* __restrict__ W3, const float* __restrict__ b3,
    const float* __restrict__ W4, const float* __restrict__ b4,
    const float* __restrict__ W5, const float* __restrict__ b5,
    const float* __restrict__ W6, const float* __restrict__ b6,
    float* __restrict__ out)
{
    __shared__ float uS[32 * PW];      // u table (layer1), overwritten with u2 (layer2)
    __shared__ float vS[32 * PW];      // v table (layer1), overwritten with v2 (layer2)
    __shared__ float aggS[32 * PW];    // h = agg/29 + b3 between layers
    __shared__ float t2S[4][32 * PW];  // wave-private round-trip buffers

    const int b    = blockIdx.x;
    const int t    = threadIdx.x;
    const int lane = t & 63;
    const int w    = t >> 6;          // wave 0..3
    const int col  = lane & 31;       // output-feature col (B/C) == pair-row j (A)
    const int h    = lane >> 5;       // k-half selector
    const int j    = col;             // A-operand row this lane supplies

    // ---- persistent B-fragments: B layout col=lane&31, k = 8*h + e (lo) / 16+8*h+e (hi)
    short8 W2lo, W2hi, W3lo, W3hi, W5lo, W5hi, W6lo, W6hi;
#pragma unroll
    for (int e = 0; e < 8; ++e) {
        const int klo = 8 * h + e, khi = 16 + 8 * h + e;
        W2lo[e] = bfb(W2[klo * H + col]);  W2hi[e] = bfb(W2[khi * H + col]);
        W3lo[e] = bfb(W3[klo * H + col]);  W3hi[e] = bfb(W3[khi * H + col]);
        W5lo[e] = bfb(W5[klo * H + col]);  W5hi[e] = bfb(W5[khi * H + col]);
        W6lo[e] = bfb(col < D ? W6[klo * D + col] : 0.0f);
        W6hi[e] = bfb(col < D ? W6[khi * D + col] : 0.0f);
    }
    const float bb2 = b2[col], bb5 = b5[col], b3c = b3[col];
    const float b6c = (col < D) ? b6[col] : 0.0f;

    // ---------------- Phase A: per-node u,v (fp32, factored W1) ----------------
    const float* xb = x + b * (N * D);
    if (t < N * 8) {
        const int i = t >> 3, gg = t & 7;
        const float x0 = xb[i*D+0], x1 = xb[i*D+1], x2 = xb[i*D+2];
#pragma unroll
        for (int ff = 0; ff < 4; ++ff) {
            const int f = gg + 8 * ff;
            const float wa0 = W1[0*H+f], wa1 = W1[1*H+f], wa2 = W1[2*H+f];
            const float wb0 = W1[3*H+f], wb1 = W1[4*H+f], wb2 = W1[5*H+f];
            vS[i*PW+f] = x0*wb0 + x1*wb1 + x2*wb2;
            uS[i*PW+f] = x0*(wa0-wb0) + x1*(wa1-wb1) + x2*(wa2-wb2) + b1[f];
        }
    }
    __syncthreads();

    float* const rt = t2S[w];

    // ================= Layer 1 =================
    {
        // v-fragment source is node-invariant: preload once
        float vlo[8], vhi[8];
#pragma unroll
        for (int e = 0; e < 8; ++e) {
            vlo[e] = vS[j*PW + 8*h + e];
            vhi[e] = vS[j*PW + 16 + 8*h + e];
        }
#pragma unroll 1
        for (int i = w; i < N; i += 4) {
            const bool alive = (j < N) && (j != i);
            const float* ur = &uS[i*PW];
            short8 alo, ahi;
#pragma unroll
            for (int e = 0; e < 8; ++e) {
                const float t0 = fmaxf(ur[8*h + e]      + vlo[e], 0.0f);
                const float t1 = fmaxf(ur[16 + 8*h + e] + vhi[e], 0.0f);
                alo[e] = alive ? bfb(t0) : (short)0;
                ahi[e] = alive ? bfb(t1) : (short)0;
            }
            float16v acc;
#pragma unroll
            for (int r = 0; r < 16; ++r) acc[r] = bb2;
            acc = mfma32(alo, W2lo, acc);
            acc = mfma32(ahi, W2hi, acc);
            // T2 = relu(acc): C layout col=col, row=(r&3)+8*(r>>2)+4*h -> round trip
#pragma unroll
            for (int r = 0; r < 16; ++r)
                rt[((r&3) + 8*(r>>2) + 4*h) * PW + col] = fmaxf(acc[r], 0.0f);
            short8 clo, chi;
#pragma unroll
            for (int e = 0; e < 8; ++e) {
                const float t0 = rt[j*PW + 8*h + e];
                const float t1 = rt[j*PW + 16 + 8*h + e];
                clo[e] = alive ? bfb(t0) : (short)0;
                chi[e] = alive ? bfb(t1) : (short)0;
            }
            float16v a2;
#pragma unroll
            for (int r = 0; r < 16; ++r) a2[r] = 0.0f;
            a2 = mfma32(clo, W3lo, a2);
            a2 = mfma32(chi, W3hi, a2);
            // aggregation = column-sum over rows (16 regs cover 16 rows; other 16 in peer half-wave)
            float s = 0.0f;
#pragma unroll
            for (int r = 0; r < 16; ++r) s += a2[r];
            s += __shfl_xor(s, 32, 64);
            if (h == 0) aggS[i*PW + col] = s * INV_CNT + b3c;   // h = agg/29 + b3
        }
    }
    __syncthreads();

    // ====== Phase C: u2 = h@(W4a-W4b)+b4 (wave0), v2 = h@W4b (wave1), via one 32x32 tile ======
    if (w < 2) {
        const bool aliveC = (j < N);
        short8 alo, ahi;
#pragma unroll
        for (int e = 0; e < 8; ++e) {
            const float t0 = aggS[j*PW + 8*h + e];
            const float t1 = aggS[j*PW + 16 + 8*h + e];
            alo[e] = aliveC ? bfb(t0) : (short)0;
            ahi[e] = aliveC ? bfb(t1) : (short)0;
        }
        short8 Flo, Fhi;
        float binit;
        if (w == 0) {
#pragma unroll
            for (int e = 0; e < 8; ++e) {
                const int klo = 8*h + e, khi = 16 + 8*h + e;
                Flo[e] = bfb(W4[klo*H + col] - W4[(H + klo)*H + col]);
                Fhi[e] = bfb(W4[khi*H + col] - W4[(H + khi)*H + col]);
            }
            binit = b4[col];
        } else {
#pragma unroll
            for (int e = 0; e < 8; ++e) {
                const int klo = 8*h + e, khi = 16 + 8*h + e;
                Flo[e] = bfb(W4[(H + klo)*H + col]);
                Fhi[e] = bfb(W4[(H + khi)*H + col]);
            }
            binit = 0.0f;
        }
        float16v acc;
#pragma unroll
        for (int r = 0; r < 16; ++r) acc[r] = binit;
        acc = mfma32(alo, Flo, acc);
        acc = mfma32(ahi, Fhi, acc);
        float* const dst = (w == 0) ? uS : vS;
#pragma unroll
        for (int r = 0; r < 16; ++r)
            dst[((r&3) + 8*(r>>2) + 4*h) * PW + col] = acc[r];
    }
    __syncthreads();

    // ================= Layer 2 =================
    {
        float vlo[8], vhi[8];
#pragma unroll
        for (int e = 0; e < 8; ++e) {
            vlo[e] = vS[j*PW + 8*h + e];
            vhi[e] = vS[j*PW + 16 + 8*h + e];
        }
#pragma unroll 1
        for (int i = w; i < N; i += 4) {
            const bool alive = (j < N) && (j != i);
            const float* ur = &uS[i*PW];
            short8 alo, ahi;
#pragma unroll
            for (int e = 0; e < 8; ++e) {
                const float t0 = fmaxf(ur[8*h + e]      + vlo[e], 0.0f);
                const float t1 = fmaxf(ur[16 + 8*h + e] + vhi[e], 0.0f);
                alo[e] = alive ? bfb(t0) : (short)0;
                ahi[e] = alive ? bfb(t1) : (short)0;
            }
            float16v acc;
#pragma unroll
            for (int r = 0; r < 16; ++r) acc[r] = bb5;
            acc = mfma32(alo, W5lo, acc);
            acc = mfma32(ahi, W5hi, acc);
#pragma unroll
            for (int r = 0; r < 16; ++r)
                rt[((r&3) + 8*(r>>2) + 4*h) * PW + col] = fmaxf(acc[r], 0.0f);
            short8 clo, chi;
#pragma unroll
            for (int e = 0; e < 8; ++e) {
                const float t0 = rt[j*PW + 8*h + e];
                const float t1 = rt[j*PW + 16 + 8*h + e];
                clo[e] = alive ? bfb(t0) : (short)0;
                chi[e] = alive ? bfb(t1) : (short)0;
            }
            float16v a2;
#pragma unroll
            for (int r = 0; r < 16; ++r) a2[r] = 0.0f;
            a2 = mfma32(clo, W6lo, a2);
            a2 = mfma32(chi, W6hi, a2);
            float s = 0.0f;
#pragma unroll
            for (int r = 0; r < 16; ++r) s += a2[r];
            s += __shfl_xor(s, 32, 64);
            if (lane < D) out[b*(N*D) + i*D + lane] = s * INV_CNT + b6c;
        }
    }
}

} // namespace

extern "C" void kernel_launch(void* const* d_in, const int* in_sizes, int n_in,
                              void* d_out, int out_size, void* d_ws, size_t ws_size,
                              hipStream_t stream) {
    const float* x  = (const float*)d_in[0];
    const float* W1 = (const float*)d_in[1];
    const float* b1 = (const float*)d_in[2];
    const float* W2 = (const float*)d_in[3];
    const float* b2 = (const float*)d_in[4];
    const float* W3 = (const float*)d_in[5];
    const float* b3 = (const float*)d_in[6];
    const float* W4 = (const float*)d_in[7];
    const float* b4 = (const float*)d_in[8];
    const float* W5 = (const float*)d_in[9];
    const float* b5 = (const float*)d_in[10];
    const float* W6 = (const float*)d_in[11];
    const float* b6 = (const float*)d_in[12];
    // d_in[13] = edge_index: dense all-pairs, structure hardcoded.

    const int batch = in_sizes[0] / (N * D);
    float* out = (float*)d_out;

    gnn2_v2<<<dim3(batch), dim3(256), 0, stream>>>(
        x, W1, b1, W2, b2, W3, b3, W4, b4, W5, b5, W6, b6, out);
}

// Round 11
// 103.209 us; speedup vs baseline: 2.6784x; 1.0789x over previous
//
#include <hip/hip_runtime.h>
#include <hip/hip_bf16.h>

namespace {

typedef __attribute__((ext_vector_type(8)))  short short8;
typedef __attribute__((ext_vector_type(16))) float float16v;
typedef __attribute__((ext_vector_type(4)))  float f4;
typedef __attribute__((ext_vector_type(4)))  int   int4v;

constexpr int N = 30;              // nodes
constexpr int H = 32;              // hidden
constexpr int D = 3;               // dims
constexpr int PW = H + 4;          // LDS row stride (words); rows 16B-aligned (144B)
constexpr float INV_CNT = 1.0f / 29.0f;

__device__ __forceinline__ short bfb(float x) {
    __hip_bfloat16 h = __float2bfloat16(x);   // RNE
    return __builtin_bit_cast(short, h);
}
__device__ __forceinline__ int pkbf(float a, float b) {
    // two scalar RNE converts + pack; compiler fuses to v_cvt_pk_bf16_f32
    // (bit_cast of __hip_bfloat162 is ill-formed: not trivially copyable)
    const unsigned lo = (unsigned short)bfb(a);
    const unsigned hi = (unsigned short)bfb(b);
    return (int)(lo | (hi << 16));
}
__device__ __forceinline__ float16v mfma32(short8 a, short8 b, float16v c) {
    return __builtin_amdgcn_mfma_f32_32x32x16_bf16(a, b, c, 0, 0, 0);
}

// Per node i: 30 pair-rows = one 32x32 tile. MFMA1 is computed TRANSPOSED
// (A=W^T-frag, B=X^T-frag) so its C-layout output has lane col = T2 row col;
// the k-halves are re-assembled in-register via 8 shfl_xor(32) — no LDS
// round-trip. MFMA2 (A=T2-frag, B=W-frag) output C-layout reg-sums into the
// aggregation. Diagonal/pad rows zeroed on the MFMA2 A-operand only.
__global__ __launch_bounds__(256, 4) void gnn2_v3(
    const float* __restrict__ x,
    const float* __restrict__ W1, const float* __restrict__ b1,
    const float* __restrict__ W2, const float* __restrict__ b2,
    const float* __restrict__ W3, const float* __restrict__ b3,
    const float* __restrict__ W4, const float* __restrict__ b4,
    const float* __restrict__ W5, const float* __restrict__ b5,
    const float* __restrict__ W6, const float* __restrict__ b6,
    float* __restrict__ out)
{
    __shared__ float uS[32 * PW];      // u table (layer1) -> u2 (layer2)
    __shared__ float vS[32 * PW];      // v table (layer1) -> v2 (layer2)
    __shared__ float aggS[32 * PW];    // h = agg/29 + b3 between layers

    const int b    = blockIdx.x;
    const int t    = threadIdx.x;
    const int lane = t & 63;
    const int w    = t >> 6;          // wave 0..3
    const int col  = lane & 31;       // B/C col == A row == pair-row j
    const int h    = lane >> 5;       // k-half selector
    const int j    = col;

    // ---- layer-1 weight fragments (same data serves as A=W^T or B=W) ----
    short8 W2lo, W2hi, W3lo, W3hi;
#pragma unroll
    for (int e = 0; e < 8; ++e) {
        const int klo = 8 * h + e, khi = 16 + 8 * h + e;
        W2lo[e] = bfb(W2[klo * H + col]);  W2hi[e] = bfb(W2[khi * H + col]);
        W3lo[e] = bfb(W3[klo * H + col]);  W3hi[e] = bfb(W3[khi * H + col]);
    }
    float b2v[16];                      // bias for transposed MFMA1: per-reg f
#pragma unroll
    for (int r = 0; r < 16; ++r) b2v[r] = b2[(r & 3) + 8 * (r >> 2) + 4 * h];
    const float b3c = b3[col];

    // ---------------- Phase A: per-node u,v (fp32, factored W1) ----------------
    const float* xb = x + b * (N * D);
    if (t < N * 8) {
        const int i = t >> 3, gg = t & 7;
        const float x0 = xb[i*D+0], x1 = xb[i*D+1], x2 = xb[i*D+2];
#pragma unroll
        for (int ff = 0; ff < 4; ++ff) {
            const int f = gg + 8 * ff;
            const float wa0 = W1[0*H+f], wa1 = W1[1*H+f], wa2 = W1[2*H+f];
            const float wb0 = W1[3*H+f], wb1 = W1[4*H+f], wb2 = W1[5*H+f];
            vS[i*PW+f] = x0*wb0 + x1*wb1 + x2*wb2;
            uS[i*PW+f] = x0*(wa0-wb0) + x1*(wa1-wb1) + x2*(wa2-wb2) + b1[f];
        }
    }
    if (t < 2 * PW) {                   // zero pad rows 30,31
        uS[30*PW + t] = 0.0f;  vS[30*PW + t] = 0.0f;  aggS[30*PW + t] = 0.0f;
    }
    __syncthreads();

    // ================= Layer 1 =================
    {
        const f4 v0 = *(const f4*)&vS[j*PW + 8*h];
        const f4 v1 = *(const f4*)&vS[j*PW + 8*h + 4];
        const f4 v2 = *(const f4*)&vS[j*PW + 16 + 8*h];
        const f4 v3 = *(const f4*)&vS[j*PW + 16 + 8*h + 4];
#pragma unroll 1
        for (int i = w; i < N; i += 4) {
            const bool alive = (j < N) && (j != i);
            const float* ur = &uS[i*PW];
            const f4 u0 = *(const f4*)(ur + 8*h);
            const f4 u1 = *(const f4*)(ur + 8*h + 4);
            const f4 u2 = *(const f4*)(ur + 16 + 8*h);
            const f4 u3 = *(const f4*)(ur + 16 + 8*h + 4);
            const short8 alo = __builtin_bit_cast(short8, (int4v){
                pkbf(fmaxf(u0[0]+v0[0],0.f), fmaxf(u0[1]+v0[1],0.f)),
                pkbf(fmaxf(u0[2]+v0[2],0.f), fmaxf(u0[3]+v0[3],0.f)),
                pkbf(fmaxf(u1[0]+v1[0],0.f), fmaxf(u1[1]+v1[1],0.f)),
                pkbf(fmaxf(u1[2]+v1[2],0.f), fmaxf(u1[3]+v1[3],0.f))});
            const short8 ahi = __builtin_bit_cast(short8, (int4v){
                pkbf(fmaxf(u2[0]+v2[0],0.f), fmaxf(u2[1]+v2[1],0.f)),
                pkbf(fmaxf(u2[2]+v2[2],0.f), fmaxf(u2[3]+v2[3],0.f)),
                pkbf(fmaxf(u3[0]+v3[0],0.f), fmaxf(u3[1]+v3[1],0.f)),
                pkbf(fmaxf(u3[2]+v3[2],0.f), fmaxf(u3[3]+v3[3],0.f))});
            float16v acc;
#pragma unroll
            for (int r = 0; r < 16; ++r) acc[r] = b2v[r];
            acc = mfma32(W2lo, alo, acc);     // transposed: acc = T2^T (C-layout)
            acc = mfma32(W2hi, ahi, acc);
            // relu + pack pairs; own regs hold k = {4h..4h+3}+8m
            const int P0 = pkbf(fmaxf(acc[0], 0.f), fmaxf(acc[1], 0.f));
            const int P1 = pkbf(fmaxf(acc[2], 0.f), fmaxf(acc[3], 0.f));
            const int P2 = pkbf(fmaxf(acc[4], 0.f), fmaxf(acc[5], 0.f));
            const int P3 = pkbf(fmaxf(acc[6], 0.f), fmaxf(acc[7], 0.f));
            const int P4 = pkbf(fmaxf(acc[8], 0.f), fmaxf(acc[9], 0.f));
            const int P5 = pkbf(fmaxf(acc[10],0.f), fmaxf(acc[11],0.f));
            const int P6 = pkbf(fmaxf(acc[12],0.f), fmaxf(acc[13],0.f));
            const int P7 = pkbf(fmaxf(acc[14],0.f), fmaxf(acc[15],0.f));
            // exchange k-halves between h-partners (lane ^ 32)
            const int sp0 = __shfl_xor(P0, 32, 64);
            const int sp1 = __shfl_xor(P1, 32, 64);
            const int sp2 = __shfl_xor(P2, 32, 64);
            const int sp3 = __shfl_xor(P3, 32, 64);
            const int sp4 = __shfl_xor(P4, 32, 64);
            const int sp5 = __shfl_xor(P5, 32, 64);
            const int sp6 = __shfl_xor(P6, 32, 64);
            const int sp7 = __shfl_xor(P7, 32, 64);
            int w0 = h ? sp2 : P0;  int w1 = h ? sp3 : P1;   // A-lo: k=8h+e
            int w2 = h ? P2 : sp0;  int w3 = h ? P3 : sp1;
            int w4 = h ? sp6 : P4;  int w5 = h ? sp7 : P5;   // A-hi: k=16+8h+e
            int w6 = h ? P6 : sp4;  int w7 = h ? P7 : sp5;
            if (!alive) { w0=0; w1=0; w2=0; w3=0; w4=0; w5=0; w6=0; w7=0; }
            const short8 a2lo = __builtin_bit_cast(short8, (int4v){w0, w1, w2, w3});
            const short8 a2hi = __builtin_bit_cast(short8, (int4v){w4, w5, w6, w7});
            float16v m2;
#pragma unroll
            for (int r = 0; r < 16; ++r) m2[r] = 0.0f;
            m2 = mfma32(a2lo, W3lo, m2);      // MSG rows in C-layout
            m2 = mfma32(a2hi, W3hi, m2);
            float s = 0.0f;
#pragma unroll
            for (int r = 0; r < 16; ++r) s += m2[r];
            s += __shfl_xor(s, 32, 64);
            if (h == 0) aggS[i*PW + col] = s * INV_CNT + b3c;
        }
    }
    __syncthreads();

    // ====== Phase C: u2 = h@(W4a-W4b)+b4 (wave0), v2 = h@W4b (wave1) ======
    if (w < 2) {
        const bool aliveC = (j < N);
        short8 alo, ahi;
#pragma unroll
        for (int e = 0; e < 8; ++e) {
            const float t0 = aggS[j*PW + 8*h + e];
            const float t1 = aggS[j*PW + 16 + 8*h + e];
            alo[e] = aliveC ? bfb(t0) : (short)0;
            ahi[e] = aliveC ? bfb(t1) : (short)0;
        }
        short8 Flo, Fhi;
        float binit;
        if (w == 0) {
#pragma unroll
            for (int e = 0; e < 8; ++e) {
                const int klo = 8*h + e, khi = 16 + 8*h + e;
                Flo[e] = bfb(W4[klo*H + col] - W4[(H + klo)*H + col]);
                Fhi[e] = bfb(W4[khi*H + col] - W4[(H + khi)*H + col]);
            }
            binit = b4[col];
        } else {
#pragma unroll
            for (int e = 0; e < 8; ++e) {
                const int klo = 8*h + e, khi = 16 + 8*h + e;
                Flo[e] = bfb(W4[(H + klo)*H + col]);
                Fhi[e] = bfb(W4[(H + khi)*H + col]);
            }
            binit = 0.0f;
        }
        float16v acc;
#pragma unroll
        for (int r = 0; r < 16; ++r) acc[r] = binit;
        acc = mfma32(alo, Flo, acc);
        acc = mfma32(ahi, Fhi, acc);
        float* const dst = (w == 0) ? uS : vS;
#pragma unroll
        for (int r = 0; r < 16; ++r)
            dst[((r&3) + 8*(r>>2) + 4*h) * PW + col] = acc[r];
    }
    __syncthreads();

    // ---- layer-2 weight fragments (built late to bound register pressure) ----
    short8 W5lo, W5hi, W6lo, W6hi;
#pragma unroll
    for (int e = 0; e < 8; ++e) {
        const int klo = 8 * h + e, khi = 16 + 8 * h + e;
        W5lo[e] = bfb(W5[klo * H + col]);  W5hi[e] = bfb(W5[khi * H + col]);
        W6lo[e] = bfb(col < D ? W6[klo * D + col] : 0.0f);
        W6hi[e] = bfb(col < D ? W6[khi * D + col] : 0.0f);
    }
    float b5v[16];
#pragma unroll
    for (int r = 0; r < 16; ++r) b5v[r] = b5[(r & 3) + 8 * (r >> 2) + 4 * h];
    const float b6c = (col < D) ? b6[col] : 0.0f;

    // ================= Layer 2 =================
    {
        const f4 v0 = *(const f4*)&vS[j*PW + 8*h];
        const f4 v1 = *(const f4*)&vS[j*PW + 8*h + 4];
        const f4 v2 = *(const f4*)&vS[j*PW + 16 + 8*h];
        const f4 v3 = *(const f4*)&vS[j*PW + 16 + 8*h + 4];
#pragma unroll 1
        for (int i = w; i < N; i += 4) {
            const bool alive = (j < N) && (j != i);
            const float* ur = &uS[i*PW];
            const f4 u0 = *(const f4*)(ur + 8*h);
            const f4 u1 = *(const f4*)(ur + 8*h + 4);
            const f4 u2 = *(const f4*)(ur + 16 + 8*h);
            const f4 u3 = *(const f4*)(ur + 16 + 8*h + 4);
            const short8 alo = __builtin_bit_cast(short8, (int4v){
                pkbf(fmaxf(u0[0]+v0[0],0.f), fmaxf(u0[1]+v0[1],0.f)),
                pkbf(fmaxf(u0[2]+v0[2],0.f), fmaxf(u0[3]+v0[3],0.f)),
                pkbf(fmaxf(u1[0]+v1[0],0.f), fmaxf(u1[1]+v1[1],0.f)),
                pkbf(fmaxf(u1[2]+v1[2],0.f), fmaxf(u1[3]+v1[3],0.f))});
            const short8 ahi = __builtin_bit_cast(short8, (int4v){
                pkbf(fmaxf(u2[0]+v2[0],0.f), fmaxf(u2[1]+v2[1],0.f)),
                pkbf(fmaxf(u2[2]+v2[2],0.f), fmaxf(u2[3]+v2[3],0.f)),
                pkbf(fmaxf(u3[0]+v3[0],0.f), fmaxf(u3[1]+v3[1],0.f)),
                pkbf(fmaxf(u3[2]+v3[2],0.f), fmaxf(u3[3]+v3[3],0.f))});
            float16v acc;
#pragma unroll
            for (int r = 0; r < 16; ++r) acc[r] = b5v[r];
            acc = mfma32(W5lo, alo, acc);     // acc = T5^T (C-layout)
            acc = mfma32(W5hi, ahi, acc);
            const int P0 = pkbf(fmaxf(acc[0], 0.f), fmaxf(acc[1], 0.f));
            const int P1 = pkbf(fmaxf(acc[2], 0.f), fmaxf(acc[3], 0.f));
            const int P2 = pkbf(fmaxf(acc[4], 0.f), fmaxf(acc[5], 0.f));
            const int P3 = pkbf(fmaxf(acc[6], 0.f), fmaxf(acc[7], 0.f));
            const int P4 = pkbf(fmaxf(acc[8], 0.f), fmaxf(acc[9], 0.f));
            const int P5 = pkbf(fmaxf(acc[10],0.f), fmaxf(acc[11],0.f));
            const int P6 = pkbf(fmaxf(acc[12],0.f), fmaxf(acc[13],0.f));
            const int P7 = pkbf(fmaxf(acc[14],0.f), fmaxf(acc[15],0.f));
            const int sp0 = __shfl_xor(P0, 32, 64);
            const int sp1 = __shfl_xor(P1, 32, 64);
            const int sp2 = __shfl_xor(P2, 32, 64);
            const int sp3 = __shfl_xor(P3, 32, 64);
            const int sp4 = __shfl_xor(P4, 32, 64);
            const int sp5 = __shfl_xor(P5, 32, 64);
            const int sp6 = __shfl_xor(P6, 32, 64);
            const int sp7 = __shfl_xor(P7, 32, 64);
            int w0 = h ? sp2 : P0;  int w1 = h ? sp3 : P1;
            int w2 = h ? P2 : sp0;  int w3 = h ? P3 : sp1;
            int w4 = h ? sp6 : P4;  int w5 = h ? sp7 : P5;
            int w6 = h ? P6 : sp4;  int w7 = h ? P7 : sp5;
            if (!alive) { w0=0; w1=0; w2=0; w3=0; w4=0; w5=0; w6=0; w7=0; }
            const short8 a2lo = __builtin_bit_cast(short8, (int4v){w0, w1, w2, w3});
            const short8 a2hi = __builtin_bit_cast(short8, (int4v){w4, w5, w6, w7});
            float16v m2;
#pragma unroll
            for (int r = 0; r < 16; ++r) m2[r] = 0.0f;
            m2 = mfma32(a2lo, W6lo, m2);
            m2 = mfma32(a2hi, W6hi, m2);
            float s = 0.0f;
#pragma unroll
            for (int r = 0; r < 16; ++r) s += m2[r];
            s += __shfl_xor(s, 32, 64);
            if (lane < D) out[b*(N*D) + i*D + lane] = s * INV_CNT + b6c;
        }
    }
}

} // namespace

extern "C" void kernel_launch(void* const* d_in, const int* in_sizes, int n_in,
                              void* d_out, int out_size, void* d_ws, size_t ws_size,
                              hipStream_t stream) {
    const float* x  = (const float*)d_in[0];
    const float* W1 = (const float*)d_in[1];
    const float* b1 = (const float*)d_in[2];
    const float* W2 = (const float*)d_in[3];
    const float* b2 = (const float*)d_in[4];
    const float* W3 = (const float*)d_in[5];
    const float* b3 = (const float*)d_in[6];
    const float* W4 = (const float*)d_in[7];
    const float* b4 = (const float*)d_in[8];
    const float* W5 = (const float*)d_in[9];
    const float* b5 = (const float*)d_in[10];
    const float* W6 = (const float*)d_in[11];
    const float* b6 = (const float*)d_in[12];
    // d_in[13] = edge_index: dense all-pairs, structure hardcoded.

    const int batch = in_sizes[0] / (N * D);
    float* out = (float*)d_out;

    gnn2_v3<<<dim3(batch), dim3(256), 0, stream>>>(
        x, W1, b1, W2, b2, W3, b3, W4, b4, W5, b5, W6, b6, out);
}